// Round 17
// baseline (11349.654 us; speedup 1.0000x reference)
//
#include <hip/hip_runtime.h>
#include <cstdio>
#include <cstdint>

// V=30000, E=512, H=512, T=32, B=64, L=512
// egfrag: bf16 hi/lo MFMA B-fragment images [t][ks:8][kt:2][nt:4][sel:2][lane:64][r:8] u16 (64 MB)
// afrag : bf16 hi/lo MFMA A-fragment images [dir][wg:256][ks:8][kt:2][sel:2][lane:64][r:8] u16 (16 MB)
// h  layout: [t][c2:256][b:64][2] f32 (64 MB per dir)
// wpack: [dir][wg:256][ks:8][sec:2][kc:16][r:8][j:4] f32 (16 MB; sec1=h used)
// R17 = R16 + (a) per-WG FLAG STORES instead of 32-way RMW sub-counters:
//   flg[dir][step][wg] 1B..1 int each; producer plain sc1 store after drain;
//   consumer wave ks polls its 32 producers' flags in parallel (128B line).
//   (b) e-fragments prefetched one full step ahead into VGPRs - the e-MFMA
//   shadow section is register+LDS only; HBM frag latency hides under a step.
// h-part stays pk-fma f32 with LDS weights (R15-proven critical path).

typedef float f32x4 __attribute__((ext_vector_type(4)));
typedef float f32x2 __attribute__((ext_vector_type(2)));
typedef short bf16x8 __attribute__((ext_vector_type(8)));
typedef unsigned short u16x4 __attribute__((ext_vector_type(4)));

#define PKFMA(ACC, W2, H2) \
    asm("v_pk_fma_f32 %0, %1, %2, %0" : "+v"(ACC) : "v"(W2), "v"(H2))

__device__ __forceinline__ unsigned short bf16_rne(float x) {
    unsigned u = __float_as_uint(x);
    return (unsigned short)((u + 0x7FFF + ((u >> 16) & 1)) >> 16);
}

// ---------------------------------------------------------------------------
// K0: embedding gather -> egfrag (bf16 hi/lo B-fragment images)
// ---------------------------------------------------------------------------
__global__ __launch_bounds__(512) void k_gather(
    const int* __restrict__ x, const float* __restrict__ emb,
    unsigned short* __restrict__ egf)
{
    const int t   = blockIdx.x;
    const int tid = threadIdx.x;
    __shared__ int xv[64];
    if (tid < 64) xv[tid] = x[tid * 512 + t];
    __syncthreads();
    #pragma unroll
    for (int i = 0; i < 16; ++i) {
        const int unit = i * 512 + tid;      // 0..8191 = (b, k-quad)
        const int b  = unit >> 7;
        const int k0 = (unit & 127) * 4;     // 4-aligned k run
        const float4 v = *reinterpret_cast<const float4*>(
            emb + (size_t)xv[b] * 512 + k0);
        const int ks   = k0 >> 6;
        const int kt   = (k0 >> 5) & 1;
        const int kk0  = k0 & 31;
        const int lgrp = (kk0 >> 2) & 3;
        const int rq   = kk0 >> 4;           // r-quad select
        const int l    = lgrp * 16 + (b & 15);
        const int nt   = b >> 4;
        const size_t base =
            ((((((size_t)t * 8 + ks) * 2 + kt) * 4 + nt) * 2 + 0) * 64 + l) * 8 + rq * 4;
        const float xs[4] = {v.x, v.y, v.z, v.w};
        u16x4 hi, lo;
        #pragma unroll
        for (int j = 0; j < 4; ++j) {
            const unsigned short h = bf16_rne(xs[j]);
            hi[j] = h;
            const float hf = __uint_as_float(((unsigned)h) << 16);
            lo[j] = bf16_rne(xs[j] - hf);
        }
        *reinterpret_cast<u16x4*>(egf + base)       = hi;   // sel 0
        *reinterpret_cast<u16x4*>(egf + base + 512) = lo;   // sel 1
    }
}

// ---------------------------------------------------------------------------
// K0b: pack f32 weights (h-section used by k_lstm)
// ---------------------------------------------------------------------------
__global__ __launch_bounds__(256) void k_pack(
    const float* __restrict__ wih_f, const float* __restrict__ whh_f,
    const float* __restrict__ wih_b, const float* __restrict__ whh_b,
    float* __restrict__ wpack)
{
    const int i = blockIdx.x * 256 + threadIdx.x;   // 0 .. 4194303
    const int j   = i & 3;
    const int r   = (i >> 2) & 7;
    const int kc  = (i >> 5) & 15;
    const int sec = (i >> 9) & 1;
    const int ks  = (i >> 10) & 7;
    const int wg  = (i >> 13) & 255;
    const int dir = (i >> 21) & 1;
    const int k   = ks * 64 + kc * 4 + j;           // 0..511
    const int g   = r >> 1, colL = r & 1;
    const int rg  = g * 512 + wg * 2 + colL;        // global gate row
    const float* wih = dir ? wih_b : wih_f;
    const float* whh = dir ? whh_b : whh_f;
    const float v = sec ? whh[(size_t)rg * 512 + k] : wih[(size_t)rg * 512 + k];
    wpack[i] = v;
}

// ---------------------------------------------------------------------------
// K0c: pack W_ih into bf16 hi/lo A-fragment images (rows 8-15 zero)
// ---------------------------------------------------------------------------
__global__ __launch_bounds__(256) void k_packA(
    const float* __restrict__ wih_f, const float* __restrict__ wih_b,
    unsigned short* __restrict__ afrag)
{
    const int idx = blockIdx.x * 256 + threadIdx.x;  // 0 .. 8388607
    const int r   = idx & 7;
    const int l   = (idx >> 3) & 63;
    const int sel = (idx >> 9) & 1;
    const int kt  = (idx >> 10) & 1;
    const int ks  = (idx >> 11) & 7;
    const int wg  = (idx >> 14) & 255;
    const int dir = (idx >> 22) & 1;
    const int i   = l & 15;
    float w = 0.f;
    if (i < 8) {
        const int rg = (i >> 1) * 512 + wg * 2 + (i & 1);
        const int k  = ks * 64 + kt * 32 + (r >> 2) * 16 + ((l >> 4) & 3) * 4 + (r & 3);
        w = (dir ? wih_b : wih_f)[(size_t)rg * 512 + k];
    }
    const unsigned short hi = bf16_rne(w);
    unsigned short outv = hi;
    if (sel) {
        const float hf = __uint_as_float(((unsigned)hi) << 16);
        outv = bf16_rne(w - hf);
    }
    afrag[idx] = outv;
}

// ---------------------------------------------------------------------------
// K1: persistent BiLSTM recurrence. 512 WGs (256/dir) x 512 threads.
// ---------------------------------------------------------------------------
__global__ __launch_bounds__(512, 2) void k_lstm(
    const unsigned short* __restrict__ egf, const float* __restrict__ wpack,
    const unsigned short* __restrict__ afrag,
    const float* __restrict__ b_f, const float* __restrict__ b_b,
    float* __restrict__ h_f, float* __restrict__ h_b,
    int* __restrict__ bar)
{
    const int bid = blockIdx.x;
    const int dir = bid >> 8;
    const int wg  = bid & 255;
    float* HH       = dir ? h_b : h_f;
    const float* BS = dir ? b_b : b_f;
    int* flg = bar + (size_t)dir * 131072;  // [step:512][wg:256] ints

    const int tid = threadIdx.x;
    const int b   = tid & 63;               // lane
    const int ks  = __builtin_amdgcn_readfirstlane(tid >> 6);   // 0..7

    __shared__ float wlds[8][512];          // 16 KB: per-wave h-weights
    __shared__ float partb[8 * 8 * 64];     // 16 KB h split-k exchange
    __shared__ float elds[2][8][8][64];     // 32 KB e split-k exchange (dbuf)
    __shared__ float hlds[64][2];           // h staging for coalesced store

    // ---- stage this wave's h-weights into LDS once (512 f32) ----
    {
        const float4* src = reinterpret_cast<const float4*>(
            wpack + (size_t)((dir * 256 + wg) * 8 + ks) * 1024 + 512);
        float4* dst = reinterpret_cast<float4*>(&wlds[ks][0]);
        #pragma unroll
        for (int i = 0; i < 2; ++i)
            dst[i * 64 + b] = src[i * 64 + b];
    }

    // ---- A-fragments (W_ih hi/lo) resident in VGPRs ----
    bf16x8 aHi[2], aLo[2];
    {
        const unsigned short* af = afrag
            + (size_t)((dir * 256 + wg) * 8 + ks) * 2048;   // [kt][sel][l][r]
        #pragma unroll
        for (int kt = 0; kt < 2; ++kt) {
            aHi[kt] = *reinterpret_cast<const bf16x8*>(af + ((kt * 2 + 0) * 64 + b) * 8);
            aLo[kt] = *reinterpret_cast<const bf16x8*>(af + ((kt * 2 + 1) * 64 + b) * 8);
        }
    }

    const int colL = (tid >> 6) & 1;    // gate-phase col (tid<128)
    float bias4[4] = {0.f, 0.f, 0.f, 0.f};
    if (tid < 128) {
        #pragma unroll
        for (int g = 0; g < 4; ++g) bias4[g] = BS[g * 512 + wg * 2 + colL];
    }
    float cst = 0.f;

    // ---- prologue: e-MFMA for step 0 -> elds[0]; prefetch frags for step 1 ----
    bf16x8 bfh[2][4], bfl[2][4];        // prefetched B-fragments (64 VGPRs)
    {
        const int t0 = dir ? 511 : 0;
        const unsigned short* ef = egf + (size_t)t0 * 65536 + (size_t)ks * 8192;
        #pragma unroll
        for (int nt = 0; nt < 4; ++nt) {
            f32x4 d = {0.f, 0.f, 0.f, 0.f};
            #pragma unroll
            for (int kt = 0; kt < 2; ++kt) {
                const bf16x8 bh = *reinterpret_cast<const bf16x8*>(
                    ef + (((kt * 4 + nt) * 2 + 0) * 64 + b) * 8);
                const bf16x8 bl = *reinterpret_cast<const bf16x8*>(
                    ef + (((kt * 4 + nt) * 2 + 1) * 64 + b) * 8);
                d = __builtin_amdgcn_mfma_f32_16x16x32_bf16(aHi[kt], bh, d, 0, 0, 0);
                d = __builtin_amdgcn_mfma_f32_16x16x32_bf16(aHi[kt], bl, d, 0, 0, 0);
                d = __builtin_amdgcn_mfma_f32_16x16x32_bf16(aLo[kt], bh, d, 0, 0, 0);
            }
            const int i0 = (b >> 4) * 4;
            if (i0 < 8) {
                #pragma unroll
                for (int g = 0; g < 4; ++g)
                    elds[0][ks][i0 + g][nt * 16 + (b & 15)] = d[g];
            }
        }
        const int t1 = dir ? 510 : 1;
        const unsigned short* ef1 = egf + (size_t)t1 * 65536 + (size_t)ks * 8192;
        #pragma unroll
        for (int kt = 0; kt < 2; ++kt)
            #pragma unroll
            for (int nt = 0; nt < 4; ++nt) {
                bfh[kt][nt] = *reinterpret_cast<const bf16x8*>(
                    ef1 + (((kt * 4 + nt) * 2 + 0) * 64 + b) * 8);
                bfl[kt][nt] = *reinterpret_cast<const bf16x8*>(
                    ef1 + (((kt * 4 + nt) * 2 + 1) * 64 + b) * 8);
            }
    }
    __syncthreads();                    // wlds + elds[0] ready

    const float* wl = &wlds[ks][0];

    for (int s = 0; s < 512; ++s) {
        const int t = dir ? (511 - s) : s;
        f32x2 acc2[8];
        #pragma unroll
        for (int r = 0; r < 8; ++r) acc2[r] = (f32x2){0.f, 0.f};

        // ---- per-wave wait: poll own 32 producers' flags in parallel ----
        if (s > 0) {
            const int* fp = flg + (size_t)(s - 1) * 256 + ks * 32 + (b & 31);
            while (__hip_atomic_load(fp, __ATOMIC_RELAXED,
                                     __HIP_MEMORY_SCOPE_AGENT) == 0)
                __builtin_amdgcn_s_sleep(1);

            const int tp = dir ? (t + 1) : (t - 1);
            const f32x2* hq = reinterpret_cast<const f32x2*>(HH)
                              + ((size_t)tp * 256 + ks * 32) * 64 + b;
            #pragma unroll
            for (int half = 0; half < 2; ++half) {
                f32x2 hv[16];
                #pragma unroll
                for (int kq = 0; kq < 16; ++kq)
                    hv[kq] = hq[(size_t)(half * 16 + kq) * 64];
                #pragma unroll
                for (int kc = 0; kc < 8; ++kc) {
                    const float* wp = wl + (half * 8 + kc) * 32;
                    #pragma unroll
                    for (int r = 0; r < 8; ++r) {
                        const f32x4 w4 = *reinterpret_cast<const f32x4*>(wp + r * 4);
                        const f32x2 wlo = __builtin_shufflevector(w4, w4, 0, 1);
                        const f32x2 whi = __builtin_shufflevector(w4, w4, 2, 3);
                        PKFMA(acc2[r], wlo, hv[kc * 2]);
                        PKFMA(acc2[r], whi, hv[kc * 2 + 1]);
                    }
                }
            }
        }

        // ---- h split-k partials ----
        #pragma unroll
        for (int r = 0; r < 8; ++r)
            partb[(ks * 8 + r) * 64 + b] = acc2[r][0] + acc2[r][1];
        __syncthreads();                 // sync1: partb + elds[s&1] ready

        // ---- gates (tid<128: colL x b) ----
        if (tid < 128) {
            float g4[4];
            #pragma unroll
            for (int g = 0; g < 4; ++g) {
                const int r = g * 2 + colL;
                float v = bias4[g];
                #pragma unroll
                for (int w = 0; w < 8; ++w) v += partb[(w * 8 + r) * 64 + b];
                #pragma unroll
                for (int w = 0; w < 8; ++w) v += elds[s & 1][w][r][b];
                g4[g] = v;
            }
            const float si = 1.f / (1.f + expf(-g4[0]));
            const float sf = 1.f / (1.f + expf(-g4[1]));
            const float tg = tanhf(g4[2]);
            const float so = 1.f / (1.f + expf(-g4[3]));
            cst = sf * cst + si * tg;
            hlds[b][colL] = so * tanhf(cst);
        }
        __syncthreads();                 // sync2: hlds ready, buffers consumed

        // ---- wave0: contiguous sc1 dwordx2 store, drain, flag store ----
        if (tid < 64) {
            f32x2 o;
            o[0] = hlds[tid][0]; o[1] = hlds[tid][1];
            float* dst = HH + (((size_t)t * 256 + wg) * 64 + tid) * 2;
            asm volatile("global_store_dwordx2 %0, %1, off sc1"
                         :: "v"(dst), "v"(o) : "memory");
            asm volatile("s_waitcnt vmcnt(0)" ::: "memory");
            if (tid == 0 && s < 511)
                __hip_atomic_store(flg + (size_t)s * 256 + wg, 1,
                                   __ATOMIC_RELAXED, __HIP_MEMORY_SCOPE_AGENT);
        }

        // ---- e-part for step s+1 via MFMA on PREFETCHED frags ----
        if (s < 511) {
            #pragma unroll
            for (int nt = 0; nt < 4; ++nt) {
                f32x4 d = {0.f, 0.f, 0.f, 0.f};
                #pragma unroll
                for (int kt = 0; kt < 2; ++kt) {
                    d = __builtin_amdgcn_mfma_f32_16x16x32_bf16(aHi[kt], bfh[kt][nt], d, 0, 0, 0);
                    d = __builtin_amdgcn_mfma_f32_16x16x32_bf16(aHi[kt], bfl[kt][nt], d, 0, 0, 0);
                    d = __builtin_amdgcn_mfma_f32_16x16x32_bf16(aLo[kt], bfh[kt][nt], d, 0, 0, 0);
                }
                const int i0 = (b >> 4) * 4;
                if (i0 < 8) {
                    #pragma unroll
                    for (int g = 0; g < 4; ++g)
                        elds[(s + 1) & 1][ks][i0 + g][nt * 16 + (b & 15)] = d[g];
                }
            }
            // prefetch frags for step s+2 (latency spans the whole next step)
            if (s < 510) {
                const int tn2 = dir ? (509 - s) : (s + 2);
                const unsigned short* ef = egf + (size_t)tn2 * 65536 + (size_t)ks * 8192;
                #pragma unroll
                for (int kt = 0; kt < 2; ++kt)
                    #pragma unroll
                    for (int nt = 0; nt < 4; ++nt) {
                        bfh[kt][nt] = *reinterpret_cast<const bf16x8*>(
                            ef + (((kt * 4 + nt) * 2 + 0) * 64 + b) * 8);
                        bfl[kt][nt] = *reinterpret_cast<const bf16x8*>(
                            ef + (((kt * 4 + nt) * 2 + 1) * 64 + b) * 8);
                    }
            }
        }
    }
}

// ---------------------------------------------------------------------------
// K2: emissions  em[t][b][tag] = [hf;hb](t,b,:) . W[tag][:] + bias
// ---------------------------------------------------------------------------
__global__ __launch_bounds__(256) void k_em(
    const float* __restrict__ hf, const float* __restrict__ hb,
    const float* __restrict__ Wm, const float* __restrict__ bias,
    float* __restrict__ em)
{
    const int t   = blockIdx.x;
    const int tid = threadIdx.x;
    const int b   = tid & 63;
    const int tg  = tid >> 6;          // 0..3 -> tags [tg*8, tg*8+8)
    __shared__ float Wl[128][33];
    float acc[8] = {};

    for (int ch = 0; ch < 8; ++ch) {
        {
            const int tag = tid >> 3;   // 0..31
            const int kq  = tid & 7;    // 0..7
            const float* src = Wm + (size_t)tag * 1024 + ch * 128 + kq * 16;
            #pragma unroll
            for (int ii = 0; ii < 4; ++ii) {
                const float4 v = *reinterpret_cast<const float4*>(src + ii * 4);
                const int k0 = kq * 16 + ii * 4;
                Wl[k0 + 0][tag] = v.x; Wl[k0 + 1][tag] = v.y;
                Wl[k0 + 2][tag] = v.z; Wl[k0 + 3][tag] = v.w;
            }
        }
        __syncthreads();
        const f32x2* hsrc2 = (ch < 4)
            ? (reinterpret_cast<const f32x2*>(hf) + ((size_t)t * 256 + ch * 64) * 64 + b)
            : (reinterpret_cast<const f32x2*>(hb) + ((size_t)t * 256 + (ch - 4) * 64) * 64 + b);
        #pragma unroll 4
        for (int c2l = 0; c2l < 64; ++c2l) {
            const f32x2 h2 = hsrc2[(size_t)c2l * 64];
            #pragma unroll
            for (int j = 0; j < 2; ++j)
                #pragma unroll
                for (int jt = 0; jt < 8; ++jt)
                    acc[jt] = fmaf(h2[j], Wl[c2l * 2 + j][tg * 8 + jt], acc[jt]);
        }
        __syncthreads();
    }

    #pragma unroll
    for (int jt = 0; jt < 8; ++jt) {
        const int tag = tg * 8 + jt;
        em[((size_t)t * 64 + b) * 32 + tag] = acc[jt] + bias[tag];
    }
}

// ---------------------------------------------------------------------------
// K3: Viterbi forward + backtrace, one wave per batch row.
// ---------------------------------------------------------------------------
__global__ __launch_bounds__(64) void k_vit(
    const float* __restrict__ em, const float* __restrict__ startv,
    const float* __restrict__ endv, const float* __restrict__ trans,
    int* __restrict__ out)
{
    const int b    = blockIdx.x;
    const int lane = threadIdx.x;
    const int c    = lane & 31;
    const bool act = lane < 32;
    __shared__ unsigned char hist[511][32];
    __shared__ int outb[512];

    float tr[32];
    #pragma unroll 8
    for (int p = 0; p < 32; ++p) tr[p] = trans[p * 32 + c];

    float s = act ? (startv[c] + em[(size_t)b * 32 + c]) : -1e30f;

    for (int t = 1; t < 512; ++t) {
        const float emc = act ? em[((size_t)t * 64 + b) * 32 + c] : 0.f;
        float m = -1e30f; int arg = 0;
        #pragma unroll 8
        for (int p = 0; p < 32; ++p) {
            const float v = __shfl(s, p) + tr[p] + emc;   // (s+tr)+em, ref order
            if (v > m) { m = v; arg = p; }                // strict > => first max
        }
        if (act) { s = m; hist[t - 1][c] = (unsigned char)arg; }
    }

    s = act ? (s + endv[c]) : -1e30f;
    int idx = act ? c : 63;
    #pragma unroll
    for (int off = 32; off >= 1; off >>= 1) {
        const float om = __shfl_down(s, off);
        const int   oi = __shfl_down(idx, off);
        if (om > s || (om == s && oi < idx)) { s = om; idx = oi; }
    }
    idx = __shfl(idx, 0);

    if (lane == 0) {
        int tag = idx;
        outb[511] = tag;
        for (int t = 510; t >= 0; --t) { tag = hist[t][tag]; outb[t] = tag; }
    }
    __syncthreads();
    for (int i = lane; i < 512; i += 64) out[(size_t)b * 512 + i] = outb[i];
}

// ---------------------------------------------------------------------------
extern "C" void kernel_launch(void* const* d_in, const int* in_sizes, int n_in,
                              void* d_out, int out_size, void* d_ws, size_t ws_size,
                              hipStream_t stream)
{
    const int*   x      = (const int*)d_in[0];
    const float* emb    = (const float*)d_in[1];
    const float* w_ih_f = (const float*)d_in[2];
    const float* w_hh_f = (const float*)d_in[3];
    const float* b_f    = (const float*)d_in[4];
    const float* w_ih_b = (const float*)d_in[5];
    const float* w_hh_b = (const float*)d_in[6];
    const float* b_b    = (const float*)d_in[7];
    const float* Wm     = (const float*)d_in[8];
    const float* bvec   = (const float*)d_in[9];
    const float* startv = (const float*)d_in[10];
    const float* endv   = (const float*)d_in[11];
    const float* trans  = (const float*)d_in[12];
    int* out = (int*)d_out;

    float* ws = (float*)d_ws;
    unsigned short* egf = (unsigned short*)ws;        // 33,554,432 u16 (64 MB)
    float* h_f   = ws + 16777216;                      // 16,777,216 f32
    float* h_b   = ws + 33554432;                      // 16,777,216 f32
    float* em    = ws + 50331648;                      //  1,048,576 f32
    float* wpack = ws + 51380224;                      //  4,194,304 f32 (16 MB)
    unsigned short* afrag = (unsigned short*)(ws + 55574528);  // 8,388,608 u16 (16 MB)
    int*   bar   = (int*)(ws + 59768832);              //  262,144 ints (1 MB flags)

    const size_t need = (size_t)(59768832 + 262144) * 4;
    if (ws_size < need) {
        fprintf(stderr, "kernel_launch: ws too small: %zu < %zu\n", ws_size, need);
        return;
    }

    (void)hipMemsetAsync(bar, 0, 1048576, stream);
    k_gather<<<dim3(512),   512, 0, stream>>>(x, emb, egf);
    k_pack  <<<dim3(16384), 256, 0, stream>>>(w_ih_f, w_hh_f, w_ih_b, w_hh_b, wpack);
    k_packA <<<dim3(32768), 256, 0, stream>>>(w_ih_f, w_ih_b, afrag);
    k_lstm  <<<dim3(512),   512, 0, stream>>>(egf, wpack, afrag, b_f, b_b,
                                              h_f, h_b, bar);
    k_em    <<<dim3(512),   256, 0, stream>>>(h_f, h_b, Wm, bvec, em);
    k_vit   <<<dim3(64),     64, 0, stream>>>(em, startv, endv, trans, out);
}

// Round 18
// 6385.027 us; speedup vs baseline: 1.7775x; 1.7775x over previous
//
#include <hip/hip_runtime.h>
#include <cstdio>
#include <cstdint>

// V=30000, E=512, H=512, T=32, B=64, L=512
// eg layout: [t][e4:128][b:64][4]   (64 MB)
// h  layout: [t][c2:256][b:64][2]   (64 MB per dir)
// em layout: [t][b][tag]            (4 MB)
// wpack: [dir][wg:256][ks:8][sec:2][kc:16][r:8][j:4]  (16 MB)
// R18 = R15 (best base: pk-fma both parts, weights in LDS, 512 WGs x 512 thr,
//   2 WGs/CU) with ONE change: sync via per-WG FLAG STORES instead of 32-way
//   RMW sub-counters. Producer: contiguous 512B dwordx2 sc1 h-store ->
//   vmcnt(0) -> one plain relaxed agent store to flg[dir][step][wg].
//   Consumer wave ks: 32 lanes poll its exact 32 producers' flags in parallel
//   (one 128B line); wave proceeds when all set. Removes the serialized
//   32-deep atomic-RMW tail from each step's critical chain.

typedef float f32x4 __attribute__((ext_vector_type(4)));
typedef float f32x2 __attribute__((ext_vector_type(2)));

#define PKFMA(ACC, W2, H2) \
    asm("v_pk_fma_f32 %0, %1, %2, %0" : "+v"(ACC) : "v"(W2), "v"(H2))

// ---------------------------------------------------------------------------
// K0: embedding gather -> eg[t][e4][b][4]
// ---------------------------------------------------------------------------
__global__ __launch_bounds__(512) void k_gather(
    const int* __restrict__ x, const float* __restrict__ emb,
    float4* __restrict__ eg4)
{
    const int t   = blockIdx.x;
    const int tid = threadIdx.x;
    __shared__ int xv[64];
    if (tid < 64) xv[tid] = x[tid * 512 + t];
    __syncthreads();
    #pragma unroll
    for (int i = 0; i < 16; ++i) {
        const int flat = i * 512 + tid;       // 0..8191
        const int b  = flat & 63;
        const int e4 = flat >> 6;             // 0..127
        const float4 v = *reinterpret_cast<const float4*>(
            emb + (size_t)xv[b] * 512 + e4 * 4);
        eg4[((size_t)t * 128 + e4) * 64 + b] = v;
    }
}

// ---------------------------------------------------------------------------
// K0b: pack weights: [dir][wg:256][ks:8][sec:2][kc:16][r:8][j:4]
// ---------------------------------------------------------------------------
__global__ __launch_bounds__(256) void k_pack(
    const float* __restrict__ wih_f, const float* __restrict__ whh_f,
    const float* __restrict__ wih_b, const float* __restrict__ whh_b,
    float* __restrict__ wpack)
{
    const int i = blockIdx.x * 256 + threadIdx.x;   // 0 .. 4194303
    const int j   = i & 3;
    const int r   = (i >> 2) & 7;
    const int kc  = (i >> 5) & 15;
    const int sec = (i >> 9) & 1;
    const int ks  = (i >> 10) & 7;
    const int wg  = (i >> 13) & 255;
    const int dir = (i >> 21) & 1;
    const int k   = ks * 64 + kc * 4 + j;           // 0..511
    const int g   = r >> 1, colL = r & 1;
    const int rg  = g * 512 + wg * 2 + colL;        // global gate row
    const float* wih = dir ? wih_b : wih_f;
    const float* whh = dir ? whh_b : whh_f;
    const float v = sec ? whh[(size_t)rg * 512 + k] : wih[(size_t)rg * 512 + k];
    wpack[i] = v;
}

// ---------------------------------------------------------------------------
// K1: persistent BiLSTM recurrence. 512 WGs (256/dir) x 512 threads.
// WG owns 2 h-cols (8 gate rows). lane = b, wave = k-slice (split-k x8).
// All weights in LDS; packed-f32 FMA. Per-wave flag-based dataflow sync.
// ---------------------------------------------------------------------------
__global__ __launch_bounds__(512, 2) void k_lstm(
    const float4* __restrict__ eg4, const float* __restrict__ wpack,
    const float* __restrict__ b_f, const float* __restrict__ b_b,
    float* __restrict__ h_f, float* __restrict__ h_b,
    int* __restrict__ bar)
{
    const int bid = blockIdx.x;
    const int dir = bid >> 8;
    const int wg  = bid & 255;
    float* HH       = dir ? h_b : h_f;
    const float* BS = dir ? b_b : b_f;
    int* flg = bar + (size_t)dir * 131072;  // [step:512][wg:256] ints

    const int tid = threadIdx.x;
    const int b   = tid & 63;
    const int ks  = __builtin_amdgcn_readfirstlane(tid >> 6);   // 0..7

    __shared__ float wlds[8][1024];     // 32 KB: per-wave [sec0:512|sec1:512]
    __shared__ float partb[8 * 8 * 64]; // 16 KB split-k exchange
    __shared__ float hlds[64][2];       // h staging for coalesced store

    // ---- stage this wave's weights into LDS once (1024 f32) ----
    {
        const float4* src = reinterpret_cast<const float4*>(
            wpack + (size_t)((dir * 256 + wg) * 8 + ks) * 1024);
        float4* dst = reinterpret_cast<float4*>(&wlds[ks][0]);
        #pragma unroll
        for (int i = 0; i < 4; ++i)
            dst[i * 64 + b] = src[i * 64 + b];
    }

    const int colL = (tid >> 6) & 1;    // gate-phase col (tid<128)
    float bias4[4] = {0.f, 0.f, 0.f, 0.f};
    if (tid < 128) {
        #pragma unroll
        for (int g = 0; g < 4; ++g) bias4[g] = BS[g * 512 + wg * 2 + colL];
    }
    float cst = 0.f;
    __syncthreads();                    // wlds ready

    const float* wl = &wlds[ks][0];

    // packed e-accumulator (lo=even-k, hi=odd-k)
    f32x2 eacc2[8];
    #pragma unroll
    for (int r = 0; r < 8; ++r) eacc2[r] = (f32x2){0.f, 0.f};

    // prologue: e-part for step 0
    {
        const int t0 = dir ? 511 : 0;
        const float4* ep = eg4 + ((size_t)t0 * 128 + ks * 16) * 64 + b;
        #pragma unroll
        for (int half = 0; half < 2; ++half) {
            f32x4 v[8];
            #pragma unroll
            for (int kc = 0; kc < 8; ++kc)
                v[kc] = *reinterpret_cast<const f32x4*>(ep + (size_t)(half * 8 + kc) * 64);
            #pragma unroll
            for (int kc = 0; kc < 8; ++kc) {
                const float* wp = wl + (half * 8 + kc) * 32;
                const f32x2 elo = __builtin_shufflevector(v[kc], v[kc], 0, 1);
                const f32x2 ehi = __builtin_shufflevector(v[kc], v[kc], 2, 3);
                #pragma unroll
                for (int r = 0; r < 8; ++r) {
                    const f32x4 w4 = *reinterpret_cast<const f32x4*>(wp + r * 4);
                    const f32x2 wlo = __builtin_shufflevector(w4, w4, 0, 1);
                    const f32x2 whi = __builtin_shufflevector(w4, w4, 2, 3);
                    PKFMA(eacc2[r], wlo, elo);
                    PKFMA(eacc2[r], whi, ehi);
                }
            }
        }
    }

    for (int s = 0; s < 512; ++s) {
        const int t = dir ? (511 - s) : s;
        f32x2 acc2[8];
        #pragma unroll
        for (int r = 0; r < 8; ++r) acc2[r] = eacc2[r];

        // ---- per-wave wait: 32 lanes poll the wave's 32 producers' flags ----
        if (s > 0) {
            const int* fp = flg + (size_t)(s - 1) * 256 + ks * 32 + (b & 31);
            while (__hip_atomic_load(fp, __ATOMIC_RELAXED,
                                     __HIP_MEMORY_SCOPE_AGENT) == 0)
                __builtin_amdgcn_s_sleep(1);

            const int tp = dir ? (t + 1) : (t - 1);
            const f32x2* hq = reinterpret_cast<const f32x2*>(HH)
                              + ((size_t)tp * 256 + ks * 32) * 64 + b;
            #pragma unroll
            for (int half = 0; half < 2; ++half) {
                f32x2 hv[16];
                #pragma unroll
                for (int kq = 0; kq < 16; ++kq)
                    hv[kq] = hq[(size_t)(half * 16 + kq) * 64];
                #pragma unroll
                for (int kc = 0; kc < 8; ++kc) {
                    const float* wp = wl + 512 + (half * 8 + kc) * 32;
                    #pragma unroll
                    for (int r = 0; r < 8; ++r) {
                        const f32x4 w4 = *reinterpret_cast<const f32x4*>(wp + r * 4);
                        const f32x2 wlo = __builtin_shufflevector(w4, w4, 0, 1);
                        const f32x2 whi = __builtin_shufflevector(w4, w4, 2, 3);
                        PKFMA(acc2[r], wlo, hv[kc * 2]);
                        PKFMA(acc2[r], whi, hv[kc * 2 + 1]);
                    }
                }
            }
        }

        // ---- split-k reduce (horizontal add once per row) ----
        #pragma unroll
        for (int r = 0; r < 8; ++r)
            partb[(ks * 8 + r) * 64 + b] = acc2[r][0] + acc2[r][1];
        __syncthreads();                 // sync1: part ready

        // ---- gates (tid<128: colL x b) ----
        if (tid < 128) {
            float g4[4];
            #pragma unroll
            for (int g = 0; g < 4; ++g) {
                const int r = g * 2 + colL;
                float v = bias4[g];
                #pragma unroll
                for (int w = 0; w < 8; ++w) v += partb[(w * 8 + r) * 64 + b];
                g4[g] = v;
            }
            const float si = 1.f / (1.f + expf(-g4[0]));
            const float sf = 1.f / (1.f + expf(-g4[1]));
            const float tg = tanhf(g4[2]);
            const float so = 1.f / (1.f + expf(-g4[3]));
            cst = sf * cst + si * tg;
            hlds[b][colL] = so * tanhf(cst);
        }
        __syncthreads();                 // sync2: hlds ready, part consumed

        // ---- wave0: contiguous sc1 dwordx2 store, drain, flag store ----
        if (tid < 64) {
            f32x2 o;
            o[0] = hlds[tid][0]; o[1] = hlds[tid][1];
            float* dst = HH + (((size_t)t * 256 + wg) * 64 + tid) * 2;
            asm volatile("global_store_dwordx2 %0, %1, off sc1"
                         :: "v"(dst), "v"(o) : "memory");
            asm volatile("s_waitcnt vmcnt(0)" ::: "memory");
            if (tid == 0 && s < 511)
                __hip_atomic_store(flg + (size_t)s * 256 + wg, 1,
                                   __ATOMIC_RELAXED, __HIP_MEMORY_SCOPE_AGENT);
        }

        // ---- e-part for step s+1 (LDS weights; off critical path) ----
        if (s < 511) {
            const int tn = dir ? (t - 1) : (t + 1);
            const float4* ep = eg4 + ((size_t)tn * 128 + ks * 16) * 64 + b;
            #pragma unroll
            for (int r = 0; r < 8; ++r) eacc2[r] = (f32x2){0.f, 0.f};
            #pragma unroll
            for (int half = 0; half < 2; ++half) {
                f32x4 v[8];
                #pragma unroll
                for (int kc = 0; kc < 8; ++kc)
                    v[kc] = *reinterpret_cast<const f32x4*>(ep + (size_t)(half * 8 + kc) * 64);
                #pragma unroll
                for (int kc = 0; kc < 8; ++kc) {
                    const float* wp = wl + (half * 8 + kc) * 32;
                    const f32x2 elo = __builtin_shufflevector(v[kc], v[kc], 0, 1);
                    const f32x2 ehi = __builtin_shufflevector(v[kc], v[kc], 2, 3);
                    #pragma unroll
                    for (int r = 0; r < 8; ++r) {
                        const f32x4 w4 = *reinterpret_cast<const f32x4*>(wp + r * 4);
                        const f32x2 wlo = __builtin_shufflevector(w4, w4, 0, 1);
                        const f32x2 whi = __builtin_shufflevector(w4, w4, 2, 3);
                        PKFMA(eacc2[r], wlo, elo);
                        PKFMA(eacc2[r], whi, ehi);
                    }
                }
            }
        }
    }
}

// ---------------------------------------------------------------------------
// K2: emissions  em[t][b][tag] = [hf;hb](t,b,:) . W[tag][:] + bias
// h layout [t][c2][b][2]
// ---------------------------------------------------------------------------
__global__ __launch_bounds__(256) void k_em(
    const float* __restrict__ hf, const float* __restrict__ hb,
    const float* __restrict__ Wm, const float* __restrict__ bias,
    float* __restrict__ em)
{
    const int t   = blockIdx.x;
    const int tid = threadIdx.x;
    const int b   = tid & 63;
    const int tg  = tid >> 6;          // 0..3 -> tags [tg*8, tg*8+8)
    __shared__ float Wl[128][33];
    float acc[8] = {};

    for (int ch = 0; ch < 8; ++ch) {
        {
            const int tag = tid >> 3;   // 0..31
            const int kq  = tid & 7;    // 0..7
            const float* src = Wm + (size_t)tag * 1024 + ch * 128 + kq * 16;
            #pragma unroll
            for (int ii = 0; ii < 4; ++ii) {
                const float4 v = *reinterpret_cast<const float4*>(src + ii * 4);
                const int k0 = kq * 16 + ii * 4;
                Wl[k0 + 0][tag] = v.x; Wl[k0 + 1][tag] = v.y;
                Wl[k0 + 2][tag] = v.z; Wl[k0 + 3][tag] = v.w;
            }
        }
        __syncthreads();
        const f32x2* hsrc2 = (ch < 4)
            ? (reinterpret_cast<const f32x2*>(hf) + ((size_t)t * 256 + ch * 64) * 64 + b)
            : (reinterpret_cast<const f32x2*>(hb) + ((size_t)t * 256 + (ch - 4) * 64) * 64 + b);
        #pragma unroll 4
        for (int c2l = 0; c2l < 64; ++c2l) {
            const f32x2 h2 = hsrc2[(size_t)c2l * 64];
            #pragma unroll
            for (int j = 0; j < 2; ++j)
                #pragma unroll
                for (int jt = 0; jt < 8; ++jt)
                    acc[jt] = fmaf(h2[j], Wl[c2l * 2 + j][tg * 8 + jt], acc[jt]);
        }
        __syncthreads();
    }

    #pragma unroll
    for (int jt = 0; jt < 8; ++jt) {
        const int tag = tg * 8 + jt;
        em[((size_t)t * 64 + b) * 32 + tag] = acc[jt] + bias[tag];
    }
}

// ---------------------------------------------------------------------------
// K3: Viterbi forward + backtrace, one wave per batch row.
// ---------------------------------------------------------------------------
__global__ __launch_bounds__(64) void k_vit(
    const float* __restrict__ em, const float* __restrict__ startv,
    const float* __restrict__ endv, const float* __restrict__ trans,
    int* __restrict__ out)
{
    const int b    = blockIdx.x;
    const int lane = threadIdx.x;
    const int c    = lane & 31;
    const bool act = lane < 32;
    __shared__ unsigned char hist[511][32];
    __shared__ int outb[512];

    float tr[32];
    #pragma unroll 8
    for (int p = 0; p < 32; ++p) tr[p] = trans[p * 32 + c];

    float s = act ? (startv[c] + em[(size_t)b * 32 + c]) : -1e30f;

    for (int t = 1; t < 512; ++t) {
        const float emc = act ? em[((size_t)t * 64 + b) * 32 + c] : 0.f;
        float m = -1e30f; int arg = 0;
        #pragma unroll 8
        for (int p = 0; p < 32; ++p) {
            const float v = __shfl(s, p) + tr[p] + emc;   // (s+tr)+em, ref order
            if (v > m) { m = v; arg = p; }                // strict > => first max
        }
        if (act) { s = m; hist[t - 1][c] = (unsigned char)arg; }
    }

    s = act ? (s + endv[c]) : -1e30f;
    int idx = act ? c : 63;
    #pragma unroll
    for (int off = 32; off >= 1; off >>= 1) {
        const float om = __shfl_down(s, off);
        const int   oi = __shfl_down(idx, off);
        if (om > s || (om == s && oi < idx)) { s = om; idx = oi; }
    }
    idx = __shfl(idx, 0);

    if (lane == 0) {
        int tag = idx;
        outb[511] = tag;
        for (int t = 510; t >= 0; --t) { tag = hist[t][tag]; outb[t] = tag; }
    }
    __syncthreads();
    for (int i = lane; i < 512; i += 64) out[(size_t)b * 512 + i] = outb[i];
}

// ---------------------------------------------------------------------------
extern "C" void kernel_launch(void* const* d_in, const int* in_sizes, int n_in,
                              void* d_out, int out_size, void* d_ws, size_t ws_size,
                              hipStream_t stream)
{
    const int*   x      = (const int*)d_in[0];
    const float* emb    = (const float*)d_in[1];
    const float* w_ih_f = (const float*)d_in[2];
    const float* w_hh_f = (const float*)d_in[3];
    const float* b_f    = (const float*)d_in[4];
    const float* w_ih_b = (const float*)d_in[5];
    const float* w_hh_b = (const float*)d_in[6];
    const float* b_b    = (const float*)d_in[7];
    const float* Wm     = (const float*)d_in[8];
    const float* bvec   = (const float*)d_in[9];
    const float* startv = (const float*)d_in[10];
    const float* endv   = (const float*)d_in[11];
    const float* trans  = (const float*)d_in[12];
    int* out = (int*)d_out;

    float* ws    = (float*)d_ws;
    float* eg    = ws;                          // 16,777,216 f32 (64 MB)
    float* h_f   = ws + 16777216;               // 16,777,216 f32
    float* h_b   = ws + 33554432;               // 16,777,216 f32
    float* em    = ws + 50331648;               //  1,048,576 f32
    float* wpack = ws + 51380224;               //  4,194,304 f32 (16 MB)
    int*   bar   = (int*)(ws + 55574528);       //  262,144 ints (1 MB flags)

    const size_t need = (size_t)(55574528 + 262144) * 4;
    if (ws_size < need) {
        fprintf(stderr, "kernel_launch: ws too small: %zu < %zu\n", ws_size, need);
        return;
    }

    (void)hipMemsetAsync(bar, 0, 1048576, stream);
    k_gather<<<dim3(512),   512, 0, stream>>>(x, emb, (float4*)eg);
    k_pack  <<<dim3(16384), 256, 0, stream>>>(w_ih_f, w_hh_f, w_ih_b, w_hh_b, wpack);
    k_lstm  <<<dim3(512),   512, 0, stream>>>((const float4*)eg, wpack, b_f, b_b,
                                              h_f, h_b, bar);
    k_em    <<<dim3(512),   256, 0, stream>>>(h_f, h_b, Wm, bvec, em);
    k_vit   <<<dim3(64),     64, 0, stream>>>(em, startv, endv, trans, out);
}